// Round 2
// baseline (4312.053 us; speedup 1.0000x reference)
//
#include <hip/hip_runtime.h>
#include <hip/hip_bf16.h>
#include <math.h>

// Problem constants (match reference)
constexpr int B = 4, S = 4096, D = 1024, H = 8, EXPF = 4;
constexpr int E = D / H;        // 128
constexpr int F = EXPF * D;     // 4096
constexpr int M = B * S;        // 16384 rows
constexpr int DC = S / 512;     // 8
constexpr int FC = 1024;        // MLP F-chunk width
constexpr int L = 64;           // scan chunk length
constexpr int NCHUNK = S / L;   // 64
constexpr int NCH = H * B * E;  // 4096 scan channels

// ---------------------------------------------------------------- LayerNorm
__global__ __launch_bounds__(256) void ln_kernel(const float* __restrict__ x,
                                                 const float* __restrict__ g,
                                                 const float* __restrict__ b,
                                                 float* __restrict__ out) {
    const int row = blockIdx.x;
    const int t = threadIdx.x;                       // 256 threads, D/4 float4s
    const float4 v = ((const float4*)(x + (size_t)row * D))[t];
    float s  = v.x + v.y + v.z + v.w;
    float ss = v.x * v.x + v.y * v.y + v.z * v.z + v.w * v.w;
#pragma unroll
    for (int off = 32; off; off >>= 1) {
        s  += __shfl_xor(s, off, 64);
        ss += __shfl_xor(ss, off, 64);
    }
    __shared__ float sm[8];
    const int wave = t >> 6, lane = t & 63;
    if (lane == 0) { sm[wave] = s; sm[4 + wave] = ss; }
    __syncthreads();
    s  = sm[0] + sm[1] + sm[2] + sm[3];
    ss = sm[4] + sm[5] + sm[6] + sm[7];
    const float mean = s * (1.0f / D);
    const float var  = ss * (1.0f / D) - mean * mean;
    const float inv  = rsqrtf(var + 1e-5f);
    const float4 gg = ((const float4*)g)[t];
    const float4 bb = ((const float4*)b)[t];
    float4 o;
    o.x = (v.x - mean) * inv * gg.x + bb.x;
    o.y = (v.y - mean) * inv * gg.y + bb.y;
    o.z = (v.z - mean) * inv * gg.z + bb.z;
    o.w = (v.w - mean) * inv * gg.w + bb.w;
    ((float4*)(out + (size_t)row * D))[t] = o;
}

// --------------------------------------------------- x2 = x + b2 (broadcast)
__global__ __launch_bounds__(256) void init_resid(const float* __restrict__ x,
                                                  const float* __restrict__ b2,
                                                  float* __restrict__ x2) {
    const int stride = gridDim.x * blockDim.x;
    const int n4 = M * D / 4;
    for (int i = blockIdx.x * blockDim.x + threadIdx.x; i < n4; i += stride) {
        const float4 v = ((const float4*)x)[i];
        const float4 bb = ((const float4*)b2)[(i * 4) & (D - 1) ? ((i & (D / 4 - 1))) : (i & (D / 4 - 1))];
        float4 o;
        o.x = v.x + bb.x; o.y = v.y + bb.y; o.z = v.z + bb.z; o.w = v.w + bb.w;
        ((float4*)x2)[i] = o;
    }
}

// ------------------------------------------------------------------- SGEMM
// C[m,n] = sum_k A[m,k] * W[n,k] (+ bias[n])
// A: [M,*] row stride lda; W: [N,*] row stride ldw; C: [M,N] row stride N.
// EPI: 0 = bias, 1 = bias+SiLU, 2 = bias+residual-add (res may alias C),
//      3 = accumulate into C (no bias)
template <int EPI>
__global__ __launch_bounds__(256) void sgemm_bt(const float* __restrict__ A,
                                                const float* __restrict__ W,
                                                const float* __restrict__ bias,
                                                const float* res,   // no restrict: may alias C
                                                float* C,           // no restrict
                                                int K, int lda, int ldw, int N) {
    __shared__ float As[8][128];
    __shared__ float Bs[8][128];
    const int t  = threadIdx.x;
    const int bn = blockIdx.x, bm = blockIdx.y;
    const int lr = t >> 1;            // 0..127 : row within tile for staging
    const int lc = (t & 1) * 4;       // 0 or 4 : k offset for staging
    const float* Ag = A + (size_t)(bm * 128 + lr) * lda + lc;
    const float* Wg = W + (size_t)(bn * 128 + lr) * ldw + lc;
    const int tx = t & 15, ty = t >> 4;

    float acc[8][8];
#pragma unroll
    for (int i = 0; i < 8; ++i)
#pragma unroll
        for (int j = 0; j < 8; ++j) acc[i][j] = 0.0f;

    for (int k0 = 0; k0 < K; k0 += 8) {
        const float4 a4 = *(const float4*)(Ag + k0);
        const float4 w4 = *(const float4*)(Wg + k0);
        __syncthreads();
        As[lc + 0][lr] = a4.x; As[lc + 1][lr] = a4.y;
        As[lc + 2][lr] = a4.z; As[lc + 3][lr] = a4.w;
        Bs[lc + 0][lr] = w4.x; Bs[lc + 1][lr] = w4.y;
        Bs[lc + 2][lr] = w4.z; Bs[lc + 3][lr] = w4.w;
        __syncthreads();
#pragma unroll
        for (int kk = 0; kk < 8; ++kk) {
            float a[8], w[8];
            *(float4*)&a[0] = *(const float4*)&As[kk][ty * 8];
            *(float4*)&a[4] = *(const float4*)&As[kk][ty * 8 + 4];
            *(float4*)&w[0] = *(const float4*)&Bs[kk][tx * 8];
            *(float4*)&w[4] = *(const float4*)&Bs[kk][tx * 8 + 4];
#pragma unroll
            for (int i = 0; i < 8; ++i)
#pragma unroll
                for (int j = 0; j < 8; ++j)
                    acc[i][j] = fmaf(a[i], w[j], acc[i][j]);
        }
    }

    const int mbase = bm * 128 + ty * 8;
    const int nbase = bn * 128 + tx * 8;
    float bv[8];
    if (EPI != 3) {
        *(float4*)&bv[0] = *(const float4*)&bias[nbase];
        *(float4*)&bv[4] = *(const float4*)&bias[nbase + 4];
    }
#pragma unroll
    for (int i = 0; i < 8; ++i) {
        const size_t roff = (size_t)(mbase + i) * N + nbase;
        float o[8];
        if (EPI == 3) {
            float c0[8];
            *(float4*)&c0[0] = *(const float4*)&C[roff];
            *(float4*)&c0[4] = *(const float4*)&C[roff + 4];
#pragma unroll
            for (int j = 0; j < 8; ++j) o[j] = acc[i][j] + c0[j];
        } else {
#pragma unroll
            for (int j = 0; j < 8; ++j) {
                float v = acc[i][j] + bv[j];
                if (EPI == 1) v = v / (1.0f + expf(-v));   // SiLU
                o[j] = v;
            }
            if (EPI == 2) {
                float r[8];
                *(float4*)&r[0] = *(const float4*)&res[roff];
                *(float4*)&r[4] = *(const float4*)&res[roff + 4];
#pragma unroll
                for (int j = 0; j < 8; ++j) o[j] += r[j];
            }
        }
        *(float4*)&C[roff]     = *(const float4*)&o[0];
        *(float4*)&C[roff + 4] = *(const float4*)&o[4];
    }
}

// --------------------------------------------------------- decayed scan
__device__ inline float head_decay(const float* decay_raw, int h) {
    const float dr = fminf(fmaxf(decay_raw[h], 0.9f), 1.0f);
    return powf(dr, 1.0f / (float)DC);
}

// K1: per-chunk local carry (no outputs)
__global__ __launch_bounds__(256) void scan_carry(const float* __restrict__ p,
                                                  const float* __restrict__ mix_w,
                                                  const float* __restrict__ decay_raw,
                                                  float* __restrict__ carry) {
    const int g = blockIdx.x * blockDim.x + threadIdx.x;  // NCH*NCHUNK
    const int e = g & (E - 1);
    const int chunk = (g >> 7) & (NCHUNK - 1);
    const int hb = g >> 13;                  // h*B + b
    const int h = hb >> 2, b = hb & 3;
    const float d = head_decay(decay_raw, h);
    const bool is_col = h < (H / 2);
    const int s0 = chunk * L;
    const float* pp = p + ((size_t)(b * S + s0)) * D + h * E + e;
    const float* mw = mix_w + h * S + s0;
    float c = 0.0f;
#pragma unroll 4
    for (int i = 0; i < L; ++i) {
        float u = pp[(size_t)i * D];
        if (!is_col) u *= mw[i];
        c = fmaf(d, c, u);
    }
    carry[chunk * NCH + hb * E + e] = c;
}

// K2: exclusive scan over chunk carries, per channel
__global__ __launch_bounds__(256) void scan_prefix(const float* __restrict__ carry,
                                                   const float* __restrict__ decay_raw,
                                                   float* __restrict__ carry_in) {
    const int ch = blockIdx.x * blockDim.x + threadIdx.x;  // 0..NCH-1
    const int h = ch >> 9;                                  // /(B*E)=512
    const float d = head_decay(decay_raw, h);
    const float dL = powf(d, (float)L);
    float c = 0.0f;
    for (int j = 0; j < NCHUNK; ++j) {
        carry_in[j * NCH + ch] = c;
        c = fmaf(dL, c, carry[j * NCH + ch]);
    }
}

// K3: rerun local scan with carry-in; write mixed in [B,S,D] layout
__global__ __launch_bounds__(256) void scan_apply(const float* __restrict__ p,
                                                  const float* __restrict__ mix_w,
                                                  const float* __restrict__ mix_b,
                                                  const float* __restrict__ decay_raw,
                                                  const float* __restrict__ carry_in,
                                                  float* __restrict__ mixed) {
    const int g = blockIdx.x * blockDim.x + threadIdx.x;
    const int e = g & (E - 1);
    const int chunk = (g >> 7) & (NCHUNK - 1);
    const int hb = g >> 13;
    const int h = hb >> 2, b = hb & 3;
    const float d = head_decay(decay_raw, h);
    const bool is_col = h < (H / 2);
    const int s0 = chunk * L;
    const float* pp = p + ((size_t)(b * S + s0)) * D + h * E + e;
    float* mo = mixed + ((size_t)(b * S + s0)) * D + h * E + e;
    const float* mw = mix_w + h * S + s0;
    const float* mb = mix_b + h * S + s0;
    float c = carry_in[chunk * NCH + hb * E + e];
#pragma unroll 4
    for (int i = 0; i < L; ++i) {
        const float w = mw[i];
        float u = pp[(size_t)i * D];
        if (!is_col) u *= w;
        c = fmaf(d, c, u);
        float o = is_col ? fmaf(w, c, mb[i]) : (c + mb[i]);
        mo[(size_t)i * D] = o;
    }
}

// ------------------------------------------------------------------ launch
extern "C" void kernel_launch(void* const* d_in, const int* in_sizes, int n_in,
                              void* d_out, int out_size, void* d_ws, size_t ws_size,
                              hipStream_t stream) {
    (void)in_sizes; (void)n_in; (void)out_size; (void)ws_size;
    const float* x         = (const float*)d_in[0];
    const float* ln1_g     = (const float*)d_in[1];
    const float* ln1_b     = (const float*)d_in[2];
    const float* w1        = (const float*)d_in[3];
    const float* b1        = (const float*)d_in[4];
    const float* w2        = (const float*)d_in[5];
    const float* b2        = (const float*)d_in[6];
    const float* ln2_g     = (const float*)d_in[7];
    const float* ln2_b     = (const float*)d_in[8];
    const float* proj_w    = (const float*)d_in[9];   // [H,E,D] -> flat [D][D]
    const float* proj_b    = (const float*)d_in[10];  // [H,E]   -> flat [D]
    const float* mix_w     = (const float*)d_in[11];  // [H,S]
    const float* mix_b     = (const float*)d_in[12];  // [H,S]
    const float* decay_raw = (const float*)d_in[13];  // [H]
    const float* out_w     = (const float*)d_in[14];  // [D,D]
    const float* out_b     = (const float*)d_in[15];  // [D]
    float* out = (float*)d_out;

    // workspace (floats): buf0[M*D] | buf1[M*D] | carry | carry_in  (~136 MB)
    float* ws       = (float*)d_ws;
    float* buf0     = ws;
    float* buf1     = buf0 + (size_t)M * D;
    float* carry    = buf1 + (size_t)M * D;
    float* carry_in = carry + (size_t)NCHUNK * NCH;
    float* x2 = out;   // residual stream 2 lives in d_out (fully rewritten each call)

    const dim3 gD(D / 128, M / 128);      // N=1024 output tiles
    const dim3 gC(FC / 128, M / 128);     // N=1024 chunk tiles

    // 1) LN1: buf0 = LN(x)
    ln_kernel<<<M, 256, 0, stream>>>(x, ln1_g, ln1_b, buf0);
    // 2) x2 = x + b2   (accumulation base for chunked GEMM2)
    init_resid<<<2048, 256, 0, stream>>>(x, b2, x2);
    // 3) MLP in 4 F-chunks: buf1 = silu(buf0@w1_c^T + b1_c); x2 += buf1@w2_c^T
    for (int c = 0; c < EXPF; ++c) {
        sgemm_bt<1><<<gC, 256, 0, stream>>>(buf0, w1 + (size_t)c * FC * D,
                                            b1 + c * FC, nullptr, buf1,
                                            D, D, D, FC);
        sgemm_bt<3><<<gD, 256, 0, stream>>>(buf1, w2 + c * FC, nullptr, nullptr,
                                            x2, FC, FC, F, D);
    }
    // 4) LN2: buf0 = LN(x2)
    ln_kernel<<<M, 256, 0, stream>>>(x2, ln2_g, ln2_b, buf0);
    // 5) p = buf0 @ proj_w^T + proj_b  -> buf1
    sgemm_bt<0><<<gD, 256, 0, stream>>>(buf0, proj_w, proj_b, nullptr, buf1,
                                        D, D, D, D);
    // 6) blocked linear scan: buf1(p) -> buf0(mixed)
    scan_carry <<<(NCH * NCHUNK) / 256, 256, 0, stream>>>(buf1, mix_w, decay_raw, carry);
    scan_prefix<<<NCH / 256, 256, 0, stream>>>(carry, decay_raw, carry_in);
    scan_apply <<<(NCH * NCHUNK) / 256, 256, 0, stream>>>(buf1, mix_w, mix_b, decay_raw,
                                                          carry_in, buf0);
    // 7) out = buf0 @ out_w^T + out_b + x2   (res aliases C; read-before-write)
    sgemm_bt<2><<<gD, 256, 0, stream>>>(buf0, out_w, out_b, x2, out, D, D, D, D);
}

// Round 3
// 977.299 us; speedup vs baseline: 4.4122x; 4.4122x over previous
//
#include <hip/hip_runtime.h>
#include <math.h>

// Problem constants (match reference)
constexpr int B = 4, S = 4096, D = 1024, H = 8, EXPF = 4;
constexpr int E = D / H;        // 128
constexpr int F = EXPF * D;     // 4096
constexpr int M = B * S;        // 16384 rows
constexpr int DC = S / 512;     // 8
constexpr int FC = 2048;        // MLP F-chunk width (2 chunks)
constexpr int L = 64;           // scan chunk length
constexpr int NCHUNK = S / L;   // 64
constexpr int NCH = H * B * E;  // 4096 scan channels

typedef _Float16 f16;
typedef f16  h8  __attribute__((ext_vector_type(8)));
typedef f16  h4  __attribute__((ext_vector_type(4)));
typedef float fx4 __attribute__((ext_vector_type(4)));

// ------------------------------------------------------- fp32 -> f16 convert
__global__ __launch_bounds__(256) void cvt_f16(const float* __restrict__ src,
                                               f16* __restrict__ dst, int n) {
    const int stride = gridDim.x * blockDim.x * 8;
    for (int i = (blockIdx.x * blockDim.x + threadIdx.x) * 8; i < n; i += stride) {
        const float4 a = *(const float4*)(src + i);
        const float4 b = *(const float4*)(src + i + 4);
        h8 o;
        o[0] = (f16)a.x; o[1] = (f16)a.y; o[2] = (f16)a.z; o[3] = (f16)a.w;
        o[4] = (f16)b.x; o[5] = (f16)b.y; o[6] = (f16)b.z; o[7] = (f16)b.w;
        *(h8*)(dst + i) = o;
    }
}

// ---------------------------------------------------------------- LayerNorm
__global__ __launch_bounds__(256) void ln_f16(const float* __restrict__ x,
                                              const float* __restrict__ g,
                                              const float* __restrict__ b,
                                              f16* __restrict__ out) {
    const int row = blockIdx.x;
    const int t = threadIdx.x;                       // 256 threads, D/4 float4s
    const float4 v = ((const float4*)(x + (size_t)row * D))[t];
    float s  = v.x + v.y + v.z + v.w;
    float ss = v.x * v.x + v.y * v.y + v.z * v.z + v.w * v.w;
#pragma unroll
    for (int off = 32; off; off >>= 1) {
        s  += __shfl_xor(s, off, 64);
        ss += __shfl_xor(ss, off, 64);
    }
    __shared__ float sm[8];
    const int wave = t >> 6, lane = t & 63;
    if (lane == 0) { sm[wave] = s; sm[4 + wave] = ss; }
    __syncthreads();
    s  = sm[0] + sm[1] + sm[2] + sm[3];
    ss = sm[4] + sm[5] + sm[6] + sm[7];
    const float mean = s * (1.0f / D);
    const float var  = ss * (1.0f / D) - mean * mean;
    const float inv  = rsqrtf(var + 1e-5f);
    const float4 gg = ((const float4*)g)[t];
    const float4 bb = ((const float4*)b)[t];
    h4 o;
    o[0] = (f16)((v.x - mean) * inv * gg.x + bb.x);
    o[1] = (f16)((v.y - mean) * inv * gg.y + bb.y);
    o[2] = (f16)((v.z - mean) * inv * gg.z + bb.z);
    o[3] = (f16)((v.w - mean) * inv * gg.w + bb.w);
    *(h4*)(out + (size_t)row * D + t * 4) = o;
}

// --------------------------------------------------- x2 = x + b2 (broadcast)
__global__ __launch_bounds__(256) void init_resid(const float* __restrict__ x,
                                                  const float* __restrict__ b2,
                                                  float* __restrict__ x2) {
    const int stride = gridDim.x * blockDim.x;
    const int n4 = M * D / 4;
    for (int i = blockIdx.x * blockDim.x + threadIdx.x; i < n4; i += stride) {
        const float4 v  = ((const float4*)x)[i];
        const float4 bb = ((const float4*)b2)[i & (D / 4 - 1)];
        float4 o;
        o.x = v.x + bb.x; o.y = v.y + bb.y; o.z = v.z + bb.z; o.w = v.w + bb.w;
        ((float4*)x2)[i] = o;
    }
}

// ---------------------------------------------------------------- f16 GEMM
// C[m,n] = sum_k A[m,k] * W[n,k] (+ bias[n])
// A: [M,*] f16 row stride lda; W: [N,*] f16 row stride ldw.
// EPI 0: +bias -> f16 C.  EPI 1: +bias, SiLU -> f16 C.
// EPI 2: +bias +res(fp32) -> fp32 C (res may alias C).
// EPI 3: accumulate into fp32 C (no bias).
// m97 structure: 128x128 tile, BK=32, 4 waves (2x2), 4x4 16x16x32 frags/wave.
template <int EPI>
__global__ __launch_bounds__(256) void hgemm_bt(const f16* __restrict__ A,
                                                const f16* __restrict__ W,
                                                const float* __restrict__ bias,
                                                const float* res,   // may alias C
                                                void* Cv,           // f16* or float*
                                                int K, int lda, int ldw, int N) {
    __shared__ f16 lA[128 * 32];
    __shared__ f16 lB[128 * 32];
    const int t = threadIdx.x;
    const int bn = blockIdx.x, bm = blockIdx.y;
    const int w = t >> 6, lane = t & 63;
    const int wr = w >> 1, wc = w & 1;          // wave 2x2 -> 64x64 sub-tile
    const int l16 = lane & 15, kg = lane >> 4;  // frag lane decomposition

    // staging: thread t covers 32 contiguous bytes: row t/2, k-offset (t&1)*16
    const int srow = t >> 1;
    const int scol = (t & 1) * 16;
    const f16* Ag = A + (size_t)(bm * 128 + srow) * lda + scol;
    const f16* Wg = W + (size_t)(bn * 128 + srow) * ldw + scol;
    f16* lAw = lA + srow * 32 + scol;
    f16* lBw = lB + srow * 32 + scol;

    fx4 acc[4][4] = {};

    for (int k0 = 0; k0 < K; k0 += 32) {
        const uint4 a0 = *(const uint4*)(Ag + k0);
        const uint4 a1 = *(const uint4*)(Ag + k0 + 8);
        const uint4 b0 = *(const uint4*)(Wg + k0);
        const uint4 b1 = *(const uint4*)(Wg + k0 + 8);
        __syncthreads();                       // previous step's reads done
        *(uint4*)lAw = a0; *(uint4*)(lAw + 8) = a1;
        *(uint4*)lBw = b0; *(uint4*)(lBw + 8) = b1;
        __syncthreads();                       // tile visible
        h8 af[4], bf[4];
#pragma unroll
        for (int m = 0; m < 4; ++m)
            af[m] = *(const h8*)(lA + (wr * 64 + m * 16 + l16) * 32 + kg * 8);
#pragma unroll
        for (int n = 0; n < 4; ++n)
            bf[n] = *(const h8*)(lB + (wc * 64 + n * 16 + l16) * 32 + kg * 8);
#pragma unroll
        for (int m = 0; m < 4; ++m)
#pragma unroll
            for (int n = 0; n < 4; ++n)
                acc[m][n] = __builtin_amdgcn_mfma_f32_16x16x32_f16(af[m], bf[n], acc[m][n], 0, 0, 0);
    }

    // epilogue: C/D frag mapping col=lane&15, row=(lane>>4)*4+j
    const int rbase = bm * 128 + wr * 64;
    const int cbase = bn * 128 + wc * 64;
#pragma unroll
    for (int m = 0; m < 4; ++m) {
#pragma unroll
        for (int n = 0; n < 4; ++n) {
            const int col = cbase + n * 16 + l16;
            float bv = 0.0f;
            if (EPI != 3) bv = bias[col];
#pragma unroll
            for (int j = 0; j < 4; ++j) {
                const int row = rbase + m * 16 + kg * 4 + j;
                const size_t off = (size_t)row * N + col;
                float v = acc[m][n][j];
                if (EPI == 3) {
                    float* C = (float*)Cv;
                    C[off] += v;
                } else {
                    v += bv;
                    if (EPI == 1) v = v / (1.0f + expf(-v));  // SiLU
                    if (EPI == 2) {
                        ((float*)Cv)[off] = v + res[off];
                    } else {
                        ((f16*)Cv)[off] = (f16)v;
                    }
                }
            }
        }
    }
}

// --------------------------------------------------------- decayed scan
__device__ inline float head_decay(const float* decay_raw, int h) {
    const float dr = fminf(fmaxf(decay_raw[h], 0.9f), 1.0f);
    return powf(dr, 1.0f / (float)DC);
}

// K1: per-chunk local carry (no outputs)
__global__ __launch_bounds__(256) void scan_carry(const f16* __restrict__ p,
                                                  const float* __restrict__ mix_w,
                                                  const float* __restrict__ decay_raw,
                                                  float* __restrict__ carry) {
    const int g = blockIdx.x * blockDim.x + threadIdx.x;  // NCH*NCHUNK
    const int e = g & (E - 1);
    const int chunk = (g >> 7) & (NCHUNK - 1);
    const int hb = g >> 13;                  // h*B + b
    const int h = hb >> 2, b = hb & 3;
    const float d = head_decay(decay_raw, h);
    const bool is_col = h < (H / 2);
    const int s0 = chunk * L;
    const f16* pp = p + ((size_t)(b * S + s0)) * D + h * E + e;
    const float* mw = mix_w + h * S + s0;
    float c = 0.0f;
#pragma unroll 4
    for (int i = 0; i < L; ++i) {
        float u = (float)pp[(size_t)i * D];
        if (!is_col) u *= mw[i];
        c = fmaf(d, c, u);
    }
    carry[chunk * NCH + hb * E + e] = c;
}

// K2: exclusive scan over chunk carries, per channel
__global__ __launch_bounds__(256) void scan_prefix(const float* __restrict__ carry,
                                                   const float* __restrict__ decay_raw,
                                                   float* __restrict__ carry_in) {
    const int ch = blockIdx.x * blockDim.x + threadIdx.x;  // 0..NCH-1
    const int h = ch >> 9;                                  // /(B*E)=512
    const float d = head_decay(decay_raw, h);
    const float dL = powf(d, (float)L);
    float c = 0.0f;
    for (int j = 0; j < NCHUNK; ++j) {
        carry_in[j * NCH + ch] = c;
        c = fmaf(dL, c, carry[j * NCH + ch]);
    }
}

// K3: rerun local scan with carry-in; write mixed (f16) in [B,S,D] layout
__global__ __launch_bounds__(256) void scan_apply(const f16* __restrict__ p,
                                                  const float* __restrict__ mix_w,
                                                  const float* __restrict__ mix_b,
                                                  const float* __restrict__ decay_raw,
                                                  const float* __restrict__ carry_in,
                                                  f16* __restrict__ mixed) {
    const int g = blockIdx.x * blockDim.x + threadIdx.x;
    const int e = g & (E - 1);
    const int chunk = (g >> 7) & (NCHUNK - 1);
    const int hb = g >> 13;
    const int h = hb >> 2, b = hb & 3;
    const float d = head_decay(decay_raw, h);
    const bool is_col = h < (H / 2);
    const int s0 = chunk * L;
    const f16* pp = p + ((size_t)(b * S + s0)) * D + h * E + e;
    f16* mo = mixed + ((size_t)(b * S + s0)) * D + h * E + e;
    const float* mw = mix_w + h * S + s0;
    const float* mb = mix_b + h * S + s0;
    float c = carry_in[chunk * NCH + hb * E + e];
#pragma unroll 4
    for (int i = 0; i < L; ++i) {
        const float w = mw[i];
        float u = (float)pp[(size_t)i * D];
        if (!is_col) u *= w;
        c = fmaf(d, c, u);
        float o = is_col ? fmaf(w, c, mb[i]) : (c + mb[i]);
        mo[(size_t)i * D] = (f16)o;
    }
}

// ------------------------------------------------------------------ launch
extern "C" void kernel_launch(void* const* d_in, const int* in_sizes, int n_in,
                              void* d_out, int out_size, void* d_ws, size_t ws_size,
                              hipStream_t stream) {
    (void)in_sizes; (void)n_in; (void)out_size; (void)ws_size;
    const float* x         = (const float*)d_in[0];
    const float* ln1_g     = (const float*)d_in[1];
    const float* ln1_b     = (const float*)d_in[2];
    const float* w1        = (const float*)d_in[3];
    const float* b1        = (const float*)d_in[4];
    const float* w2        = (const float*)d_in[5];
    const float* b2        = (const float*)d_in[6];
    const float* ln2_g     = (const float*)d_in[7];
    const float* ln2_b     = (const float*)d_in[8];
    const float* proj_w    = (const float*)d_in[9];   // [H,E,D] -> flat [D][D]
    const float* proj_b    = (const float*)d_in[10];  // [H,E]   -> flat [D]
    const float* mix_w     = (const float*)d_in[11];  // [H,S]
    const float* mix_b     = (const float*)d_in[12];  // [H,S]
    const float* decay_raw = (const float*)d_in[13];  // [H]
    const float* out_w     = (const float*)d_in[14];  // [D,D]
    const float* out_b     = (const float*)d_in[15];  // [D]
    float* out = (float*)d_out;

    // workspace (f16 unless noted), ~124 MB total:
    // lnbuf[M*D] | actc[M*FC] | w1f[F*D] | w2f[D*F] | pjf[D*D] | owf[D*D] | carries(f32)
    f16* lnbuf = (f16*)d_ws;
    f16* actc  = lnbuf + (size_t)M * D;
    f16* w1f   = actc + (size_t)M * FC;
    f16* w2f   = w1f + (size_t)F * D;
    f16* pjf   = w2f + (size_t)D * F;
    f16* owf   = pjf + (size_t)D * D;
    float* carry    = (float*)(owf + (size_t)D * D);
    float* carry_in = carry + (size_t)NCHUNK * NCH;
    f16* p     = actc;    // proj output reuses actc region (free after MLP)
    f16* mixed = lnbuf;   // scan output reuses lnbuf region (free after proj)
    float* x2  = out;     // residual stream 2 lives in d_out (rewritten each call)

    // 0) weights fp32 -> f16 (once per call, ~10 us)
    cvt_f16<<<1024, 256, 0, stream>>>(w1, w1f, F * D);
    cvt_f16<<<1024, 256, 0, stream>>>(w2, w2f, D * F);
    cvt_f16<<<256, 256, 0, stream>>>(proj_w, pjf, D * D);
    cvt_f16<<<256, 256, 0, stream>>>(out_w, owf, D * D);
    // 1) LN1: lnbuf = LN(x)  (f16)
    ln_f16<<<M, 256, 0, stream>>>(x, ln1_g, ln1_b, lnbuf);
    // 2) x2 = x + b2 (accumulation base)
    init_resid<<<2048, 256, 0, stream>>>(x, b2, x2);
    // 3) MLP in 2 F-chunks: actc = silu(lnbuf@w1_c^T + b1_c); x2 += actc@w2_c^T
    for (int c = 0; c < F / FC; ++c) {
        hgemm_bt<1><<<dim3(FC / 128, M / 128), 256, 0, stream>>>(
            lnbuf, w1f + (size_t)c * FC * D, b1 + c * FC, nullptr, actc, D, D, D, FC);
        hgemm_bt<3><<<dim3(D / 128, M / 128), 256, 0, stream>>>(
            actc, w2f + c * FC, nullptr, nullptr, x2, FC, FC, F, D);
    }
    // 4) LN2: lnbuf = LN(x2)  (f16)
    ln_f16<<<M, 256, 0, stream>>>(x2, ln2_g, ln2_b, lnbuf);
    // 5) p = lnbuf @ proj_w^T + proj_b  (f16, into actc region)
    hgemm_bt<0><<<dim3(D / 128, M / 128), 256, 0, stream>>>(
        lnbuf, pjf, proj_b, nullptr, p, D, D, D, D);
    // 6) blocked linear scan: p -> mixed (f16, into lnbuf region)
    scan_carry <<<(NCH * NCHUNK) / 256, 256, 0, stream>>>(p, mix_w, decay_raw, carry);
    scan_prefix<<<NCH / 256, 256, 0, stream>>>(carry, decay_raw, carry_in);
    scan_apply <<<(NCH * NCHUNK) / 256, 256, 0, stream>>>(p, mix_w, mix_b, decay_raw,
                                                          carry_in, mixed);
    // 7) out = mixed @ out_w^T + out_b + x2  (res aliases C; read-before-write)
    hgemm_bt<2><<<dim3(D / 128, M / 128), 256, 0, stream>>>(
        mixed, owf, out_b, x2, out, D, D, D, D);
}

// Round 5
// 914.788 us; speedup vs baseline: 4.7137x; 1.0683x over previous
//
#include <hip/hip_runtime.h>
#include <math.h>

// Problem constants (match reference)
constexpr int B = 4, S = 4096, D = 1024, H = 8, EXPF = 4;
constexpr int E = D / H;        // 128
constexpr int F = EXPF * D;     // 4096
constexpr int M = B * S;        // 16384 rows
constexpr int DC = S / 512;     // 8
constexpr int FC = 2048;        // MLP F-chunk width (2 chunks)
constexpr int L = 64;           // scan chunk length
constexpr int NCHUNK = S / L;   // 64
constexpr int NCH = H * B * E;  // 4096 scan channels

typedef _Float16 f16;
typedef f16  h8  __attribute__((ext_vector_type(8)));
typedef f16  h4  __attribute__((ext_vector_type(4)));
typedef float fx4 __attribute__((ext_vector_type(4)));

// async global->LDS, 16B per lane; lds dest is wave-uniform base + lane*16
__device__ inline void gld16(const f16* g, f16* l) {
    __builtin_amdgcn_global_load_lds(
        (const __attribute__((address_space(1))) unsigned int*)g,
        (__attribute__((address_space(3))) unsigned int*)l, 16, 0, 0);
}

// ------------------------------------------------------- fp32 -> f16 convert
__global__ __launch_bounds__(256) void cvt_f16(const float* __restrict__ src,
                                               f16* __restrict__ dst, int n) {
    const int stride = gridDim.x * blockDim.x * 8;
    for (int i = (blockIdx.x * blockDim.x + threadIdx.x) * 8; i < n; i += stride) {
        const float4 a = *(const float4*)(src + i);
        const float4 b = *(const float4*)(src + i + 4);
        h8 o;
        o[0] = (f16)a.x; o[1] = (f16)a.y; o[2] = (f16)a.z; o[3] = (f16)a.w;
        o[4] = (f16)b.x; o[5] = (f16)b.y; o[6] = (f16)b.z; o[7] = (f16)b.w;
        *(h8*)(dst + i) = o;
    }
}

// ---------------------------------------------------------------- LayerNorm
__global__ __launch_bounds__(256) void ln_f16(const float* __restrict__ x,
                                              const float* __restrict__ g,
                                              const float* __restrict__ b,
                                              f16* __restrict__ out) {
    const int row = blockIdx.x;
    const int t = threadIdx.x;                       // 256 threads, D/4 float4s
    const float4 v = ((const float4*)(x + (size_t)row * D))[t];
    float s  = v.x + v.y + v.z + v.w;
    float ss = v.x * v.x + v.y * v.y + v.z * v.z + v.w * v.w;
#pragma unroll
    for (int off = 32; off; off >>= 1) {
        s  += __shfl_xor(s, off, 64);
        ss += __shfl_xor(ss, off, 64);
    }
    __shared__ float sm[8];
    const int wave = t >> 6, lane = t & 63;
    if (lane == 0) { sm[wave] = s; sm[4 + wave] = ss; }
    __syncthreads();
    s  = sm[0] + sm[1] + sm[2] + sm[3];
    ss = sm[4] + sm[5] + sm[6] + sm[7];
    const float mean = s * (1.0f / D);
    const float var  = ss * (1.0f / D) - mean * mean;
    const float inv  = rsqrtf(var + 1e-5f);
    const float4 gg = ((const float4*)g)[t];
    const float4 bb = ((const float4*)b)[t];
    h4 o;
    o[0] = (f16)((v.x - mean) * inv * gg.x + bb.x);
    o[1] = (f16)((v.y - mean) * inv * gg.y + bb.y);
    o[2] = (f16)((v.z - mean) * inv * gg.z + bb.z);
    o[3] = (f16)((v.w - mean) * inv * gg.w + bb.w);
    *(h4*)(out + (size_t)row * D + t * 4) = o;
}

// ---------------------------------------------------------------- f16 GEMM
// C[m,n] = sum_k A[m,k] * W[n,k] (+ bias[n])
// A: [M,*] f16 row stride lda; W: [N,*] f16 row stride ldw.
// EPI 0: +bias -> f16 C.  EPI 1: +bias, SiLU -> f16 C.
// EPI 2: +bias +res(fp32) -> fp32 C (res may alias C).
// EPI 3: accumulate into fp32 C (no bias).
// m97 structure: 128x128 tile, BK=32, 4 waves (2x2), 4x4 16x16x32 frags/wave,
// global_load_lds width-16 staging into linear LDS (m151: +35% vs reg-staged).
template <int EPI>
__global__ __launch_bounds__(256) void hgemm_bt(const f16* __restrict__ A,
                                                const f16* __restrict__ W,
                                                const float* __restrict__ bias,
                                                const float* res,   // may alias C
                                                void* Cv,           // f16* or float*
                                                int K, int lda, int ldw, int N) {
    __shared__ f16 lA[128 * 32];
    __shared__ f16 lB[128 * 32];
    const int t = threadIdx.x;
    const int bn = blockIdx.x, bm = blockIdx.y;
    const int w = t >> 6, lane = t & 63;
    const int wr = w >> 1, wc = w & 1;          // wave 2x2 -> 64x64 sub-tile
    const int l16 = lane & 15, kg = lane >> 4;  // frag lane decomposition

    // staging via global_load_lds: tile 128x32 f16 = 8KB = 8 segments of
    // 1KB (64 lanes x 16B). Wave w owns segments w*2, w*2+1 of each tile.
    // Within a segment: lane covers row = seg*16 + lane/4, col = (lane&3)*8.
    const int sA = w * 2;
    const int srow = (lane >> 2);          // 0..15
    const int scol = (lane & 3) * 8;       // 0,8,16,24
    const f16* gA0 = A + (size_t)(bm * 128 + sA * 16 + srow) * lda + scol;
    const f16* gA1 = gA0 + (size_t)16 * lda;
    const f16* gB0 = W + (size_t)(bn * 128 + sA * 16 + srow) * ldw + scol;
    const f16* gB1 = gB0 + (size_t)16 * ldw;
    f16* lA0 = lA + sA * 512;              // wave-uniform LDS bases
    f16* lA1 = lA0 + 512;
    f16* lB0 = lB + sA * 512;
    f16* lB1 = lB0 + 512;

    fx4 acc[4][4] = {};

    for (int k0 = 0; k0 < K; k0 += 32) {
        __syncthreads();                   // previous step's reads done
        gld16(gA0 + k0, lA0);
        gld16(gA1 + k0, lA1);
        gld16(gB0 + k0, lB0);
        gld16(gB1 + k0, lB1);
        __syncthreads();                   // drains vmcnt -> tile visible
        h8 af[4], bf[4];
#pragma unroll
        for (int m = 0; m < 4; ++m)
            af[m] = *(const h8*)(lA + (wr * 64 + m * 16 + l16) * 32 + kg * 8);
#pragma unroll
        for (int n = 0; n < 4; ++n)
            bf[n] = *(const h8*)(lB + (wc * 64 + n * 16 + l16) * 32 + kg * 8);
#pragma unroll
        for (int m = 0; m < 4; ++m)
#pragma unroll
            for (int n = 0; n < 4; ++n)
                acc[m][n] = __builtin_amdgcn_mfma_f32_16x16x32_f16(af[m], bf[n], acc[m][n], 0, 0, 0);
    }

    // epilogue: C/D frag mapping col=lane&15, row=(lane>>4)*4+j
    const int rbase = bm * 128 + wr * 64;
    const int cbase = bn * 128 + wc * 64;
#pragma unroll
    for (int m = 0; m < 4; ++m) {
#pragma unroll
        for (int n = 0; n < 4; ++n) {
            const int col = cbase + n * 16 + l16;
            float bv = 0.0f;
            if (EPI != 3) bv = bias[col];
#pragma unroll
            for (int j = 0; j < 4; ++j) {
                const int row = rbase + m * 16 + kg * 4 + j;
                const size_t off = (size_t)row * N + col;
                float v = acc[m][n][j];
                if (EPI == 3) {
                    float* C = (float*)Cv;
                    C[off] += v;
                } else {
                    v += bv;
                    if (EPI == 1) v = v / (1.0f + expf(-v));  // SiLU
                    if (EPI == 2) {
                        ((float*)Cv)[off] = v + res[off];
                    } else {
                        ((f16*)Cv)[off] = (f16)v;
                    }
                }
            }
        }
    }
}

// --------------------------------------------------------- decayed scan
__device__ inline float head_decay(const float* decay_raw, int h) {
    const float dr = fminf(fmaxf(decay_raw[h], 0.9f), 1.0f);
    return powf(dr, 1.0f / (float)DC);
}

// K1: per-chunk local carry (no outputs)
__global__ __launch_bounds__(256) void scan_carry(const f16* __restrict__ p,
                                                  const float* __restrict__ mix_w,
                                                  const float* __restrict__ decay_raw,
                                                  float* __restrict__ carry) {
    const int g = blockIdx.x * blockDim.x + threadIdx.x;  // NCH*NCHUNK
    const int e = g & (E - 1);
    const int chunk = (g >> 7) & (NCHUNK - 1);
    const int hb = g >> 13;                  // h*B + b
    const int h = hb >> 2, b = hb & 3;
    const float d = head_decay(decay_raw, h);
    const bool is_col = h < (H / 2);
    const int s0 = chunk * L;
    const f16* pp = p + ((size_t)(b * S + s0)) * D + h * E + e;
    const float* mw = mix_w + h * S + s0;
    float c = 0.0f;
#pragma unroll 4
    for (int i = 0; i < L; ++i) {
        float u = (float)pp[(size_t)i * D];
        if (!is_col) u *= mw[i];
        c = fmaf(d, c, u);
    }
    carry[chunk * NCH + hb * E + e] = c;
}

// K2: exclusive scan over chunk carries, per channel
__global__ __launch_bounds__(256) void scan_prefix(const float* __restrict__ carry,
                                                   const float* __restrict__ decay_raw,
                                                   float* __restrict__ carry_in) {
    const int ch = blockIdx.x * blockDim.x + threadIdx.x;  // 0..NCH-1
    const int h = ch >> 9;                                  // /(B*E)=512
    const float d = head_decay(decay_raw, h);
    const float dL = powf(d, (float)L);
    float c = 0.0f;
    for (int j = 0; j < NCHUNK; ++j) {
        carry_in[j * NCH + ch] = c;
        c = fmaf(dL, c, carry[j * NCH + ch]);
    }
}

// K3: rerun local scan with carry-in; write mixed (f16) in [B,S,D] layout
__global__ __launch_bounds__(256) void scan_apply(const f16* __restrict__ p,
                                                  const float* __restrict__ mix_w,
                                                  const float* __restrict__ mix_b,
                                                  const float* __restrict__ decay_raw,
                                                  const float* __restrict__ carry_in,
                                                  f16* __restrict__ mixed) {
    const int g = blockIdx.x * blockDim.x + threadIdx.x;
    const int e = g & (E - 1);
    const int chunk = (g >> 7) & (NCHUNK - 1);
    const int hb = g >> 13;
    const int h = hb >> 2, b = hb & 3;
    const float d = head_decay(decay_raw, h);
    const bool is_col = h < (H / 2);
    const int s0 = chunk * L;
    const f16* pp = p + ((size_t)(b * S + s0)) * D + h * E + e;
    f16* mo = mixed + ((size_t)(b * S + s0)) * D + h * E + e;
    const float* mw = mix_w + h * S + s0;
    const float* mb = mix_b + h * S + s0;
    float c = carry_in[chunk * NCH + hb * E + e];
#pragma unroll 4
    for (int i = 0; i < L; ++i) {
        const float w = mw[i];
        float u = (float)pp[(size_t)i * D];
        if (!is_col) u *= w;
        c = fmaf(d, c, u);
        float o = is_col ? fmaf(w, c, mb[i]) : (c + mb[i]);
        mo[(size_t)i * D] = (f16)o;
    }
}

// ------------------------------------------------------------------ launch
extern "C" void kernel_launch(void* const* d_in, const int* in_sizes, int n_in,
                              void* d_out, int out_size, void* d_ws, size_t ws_size,
                              hipStream_t stream) {
    (void)in_sizes; (void)n_in; (void)out_size; (void)ws_size;
    const float* x         = (const float*)d_in[0];
    const float* ln1_g     = (const float*)d_in[1];
    const float* ln1_b     = (const float*)d_in[2];
    const float* w1        = (const float*)d_in[3];
    const float* b1        = (const float*)d_in[4];
    const float* w2        = (const float*)d_in[5];
    const float* b2        = (const float*)d_in[6];
    const float* ln2_g     = (const float*)d_in[7];
    const float* ln2_b     = (const float*)d_in[8];
    const float* proj_w    = (const float*)d_in[9];   // [H,E,D] -> flat [D][D]
    const float* proj_b    = (const float*)d_in[10];  // [H,E]   -> flat [D]
    const float* mix_w     = (const float*)d_in[11];  // [H,S]
    const float* mix_b     = (const float*)d_in[12];  // [H,S]
    const float* decay_raw = (const float*)d_in[13];  // [H]
    const float* out_w     = (const float*)d_in[14];  // [D,D]
    const float* out_b     = (const float*)d_in[15];  // [D]
    float* out = (float*)d_out;

    // workspace (f16 unless noted), ~119 MB total:
    // lnbuf[M*D] | actc[M*FC] | w1f[F*D] | w2f[D*F] | pjf[D*D] | owf[D*D] | carries(f32)
    f16* lnbuf = (f16*)d_ws;
    f16* actc  = lnbuf + (size_t)M * D;
    f16* w1f   = actc + (size_t)M * FC;
    f16* w2f   = w1f + (size_t)F * D;
    f16* pjf   = w2f + (size_t)D * F;
    f16* owf   = pjf + (size_t)D * D;
    float* carry    = (float*)(owf + (size_t)D * D);
    float* carry_in = carry + (size_t)NCHUNK * NCH;
    f16* p     = actc;    // proj output reuses actc region (free after MLP)
    f16* mixed = lnbuf;   // scan output reuses lnbuf region (free after proj)
    float* x2  = out;     // residual stream 2 lives in d_out (rewritten each call)

    // 0) weights fp32 -> f16 (once per call, ~10 us)
    cvt_f16<<<1024, 256, 0, stream>>>(w1, w1f, F * D);
    cvt_f16<<<1024, 256, 0, stream>>>(w2, w2f, D * F);
    cvt_f16<<<256, 256, 0, stream>>>(proj_w, pjf, D * D);
    cvt_f16<<<256, 256, 0, stream>>>(out_w, owf, D * D);
    // 1) LN1: lnbuf = LN(x)  (f16)
    ln_f16<<<M, 256, 0, stream>>>(x, ln1_g, ln1_b, lnbuf);
    // 2) MLP in 2 F-chunks: actc = silu(lnbuf@w1_c^T + b1_c);
    //    chunk 0: x2 = actc@w2_0^T + b2 + x   (EPI2 initializes x2)
    //    chunk 1: x2 += actc@w2_1^T           (EPI3 accumulate)
    hgemm_bt<1><<<dim3(FC / 128, M / 128), 256, 0, stream>>>(
        lnbuf, w1f, b1, nullptr, actc, D, D, D, FC);
    hgemm_bt<2><<<dim3(D / 128, M / 128), 256, 0, stream>>>(
        actc, w2f, b2, x, x2, FC, FC, F, D);
    hgemm_bt<1><<<dim3(FC / 128, M / 128), 256, 0, stream>>>(
        lnbuf, w1f + (size_t)FC * D, b1 + FC, nullptr, actc, D, D, D, FC);
    hgemm_bt<3><<<dim3(D / 128, M / 128), 256, 0, stream>>>(
        actc, w2f + FC, nullptr, nullptr, x2, FC, FC, F, D);
    // 3) LN2: lnbuf = LN(x2)  (f16)
    ln_f16<<<M, 256, 0, stream>>>(x2, ln2_g, ln2_b, lnbuf);
    // 4) p = lnbuf @ proj_w^T + proj_b  (f16, into actc region)
    hgemm_bt<0><<<dim3(D / 128, M / 128), 256, 0, stream>>>(
        lnbuf, pjf, proj_b, nullptr, p, D, D, D, D);
    // 5) blocked linear scan: p -> mixed (f16, into lnbuf region)
    scan_carry <<<(NCH * NCHUNK) / 256, 256, 0, stream>>>(p, mix_w, decay_raw, carry);
    scan_prefix<<<NCH / 256, 256, 0, stream>>>(carry, decay_raw, carry_in);
    scan_apply <<<(NCH * NCHUNK) / 256, 256, 0, stream>>>(p, mix_w, mix_b, decay_raw,
                                                          carry_in, mixed);
    // 6) out = mixed @ out_w^T + out_b + x2  (res aliases C; read-before-write)
    hgemm_bt<2><<<dim3(D / 128, M / 128), 256, 0, stream>>>(
        mixed, owf, out_b, x2, out, D, D, D, D);
}

// Round 8
// 719.742 us; speedup vs baseline: 5.9911x; 1.2710x over previous
//
#include <hip/hip_runtime.h>
#include <math.h>

// Problem constants (match reference)
constexpr int B = 4, S = 4096, D = 1024, H = 8, EXPF = 4;
constexpr int E = D / H;        // 128
constexpr int F = EXPF * D;     // 4096
constexpr int M = B * S;        // 16384 rows
constexpr int DC = S / 512;     // 8
constexpr int FC = 2048;        // MLP F-chunk width (2 chunks)
constexpr int L = 64;           // scan chunk length
constexpr int NCHUNK = S / L;   // 64
constexpr int NCH = H * B * E;  // 4096 scan channels

typedef _Float16 f16;
typedef f16  h8  __attribute__((ext_vector_type(8)));
typedef f16  h4  __attribute__((ext_vector_type(4)));
typedef float fx4 __attribute__((ext_vector_type(4)));

// async global->LDS, 16B per lane; lds dest is wave-uniform base + lane*16
__device__ __forceinline__ void gld16(const f16* g, f16* l) {
    __builtin_amdgcn_global_load_lds(
        (const __attribute__((address_space(1))) unsigned int*)g,
        (__attribute__((address_space(3))) unsigned int*)l, 16, 0, 0);
}

// ------------------------------------------------------- fp32 -> f16 convert
__global__ __launch_bounds__(256) void cvt_f16(const float* __restrict__ src,
                                               f16* __restrict__ dst, int n) {
    const int stride = gridDim.x * blockDim.x * 8;
    for (int i = (blockIdx.x * blockDim.x + threadIdx.x) * 8; i < n; i += stride) {
        const float4 a = *(const float4*)(src + i);
        const float4 b = *(const float4*)(src + i + 4);
        h8 o;
        o[0] = (f16)a.x; o[1] = (f16)a.y; o[2] = (f16)a.z; o[3] = (f16)a.w;
        o[4] = (f16)b.x; o[5] = (f16)b.y; o[6] = (f16)b.z; o[7] = (f16)b.w;
        *(h8*)(dst + i) = o;
    }
}

// ---------------------------------------------------------------- LayerNorm
__global__ __launch_bounds__(256) void ln_f16(const float* __restrict__ x,
                                              const float* __restrict__ g,
                                              const float* __restrict__ b,
                                              f16* __restrict__ out) {
    const int row = blockIdx.x;
    const int t = threadIdx.x;                       // 256 threads, D/4 float4s
    const float4 v = ((const float4*)(x + (size_t)row * D))[t];
    float s  = v.x + v.y + v.z + v.w;
    float ss = v.x * v.x + v.y * v.y + v.z * v.z + v.w * v.w;
#pragma unroll
    for (int off = 32; off; off >>= 1) {
        s  += __shfl_xor(s, off, 64);
        ss += __shfl_xor(ss, off, 64);
    }
    __shared__ float sm[8];
    const int wave = t >> 6, lane = t & 63;
    if (lane == 0) { sm[wave] = s; sm[4 + wave] = ss; }
    __syncthreads();
    s  = sm[0] + sm[1] + sm[2] + sm[3];
    ss = sm[4] + sm[5] + sm[6] + sm[7];
    const float mean = s * (1.0f / D);
    const float var  = ss * (1.0f / D) - mean * mean;
    const float inv  = rsqrtf(var + 1e-5f);
    const float4 gg = ((const float4*)g)[t];
    const float4 bb = ((const float4*)b)[t];
    h4 o;
    o[0] = (f16)((v.x - mean) * inv * gg.x + bb.x);
    o[1] = (f16)((v.y - mean) * inv * gg.y + bb.y);
    o[2] = (f16)((v.z - mean) * inv * gg.z + bb.z);
    o[3] = (f16)((v.w - mean) * inv * gg.w + bb.w);
    *(h4*)(out + (size_t)row * D + t * 4) = o;
}

// ============================================================ 256x256 8-phase
// C[m,n] = sum_k A[m,k]*W[n,k] (+bias). 8 waves (2Mx4N), BK=64, dbuf LDS.
// Regions (16KB): A[db][mh], B[db][nh]. Stage schedule (2 vm-loads each):
//   ph1:A[1][1]<-t1  ph2:B[1][0],B[1][1]<-t1  ph3:A[0][0]<-n0  ph4:B[0][0]<-n0
//   ph5:A[0][1]<-n0  ph6:B[0][1]<-n0  ph8:A[1][0]<-n1
// FIFO-vmcnt ledger: ph4-end vmcnt(4) drains all db1<-t1 (pending A00,B00<-n0);
// ph8-end vmcnt(2) drains all db0<-n0 (pending A10<-n1 = prologue invariant).
// Last iter: no n0 stages -> ph4 must fully drain (vmcnt 0). Never vmcnt(0)
// mid-loop otherwise (T4). Every stage >=2 barriers after region's last read.
// T2 swizzle: LDS[row][slot] holds global k-slot (slot^(row&7)); stage source
// pre-swizzled, ds_read XORs (l16&7)<<4; rows at every read site == l16 mod 8.
// EPI 0: +bias->f16. 1: +bias,SiLU->f16. 2: +bias+res->f32 (res may alias C).
// 3: accumulate into f32 C.
#define BAR  __builtin_amdgcn_s_barrier()
#define LGK0 asm volatile("s_waitcnt lgkmcnt(0)" ::: "memory")
#define VMC4 asm volatile("s_waitcnt vmcnt(4)" ::: "memory")
#define VMC2 asm volatile("s_waitcnt vmcnt(2)" ::: "memory")
#define VMC0 asm volatile("s_waitcnt vmcnt(0)" ::: "memory")

template <int EPI>
__global__ __launch_bounds__(512, 2) void hgemm256(const f16* __restrict__ A,
                                                   const f16* __restrict__ W,
                                                   const float* __restrict__ bias,
                                                   const float* res,  // may alias C
                                                   void* Cv,          // f16* or float*
                                                   int K, int lda, int ldw, int N) {
    __shared__ __align__(16) char lds[131072];  // 8 x 16KB regions
    const int t = threadIdx.x;
    const int wid = t >> 6, lane = t & 63;
    const int wr = wid >> 2, wc = wid & 3;      // 2 x 4 wave grid
    const int l16 = lane & 15, kg = lane >> 4;
    const int bn = blockIdx.x, bm = blockIdx.y;
    const int nh = wc >> 1;                     // this wave's B region half

    // ds_read per-lane constants (swizzled)
    const int kx0 = (kg << 4) ^ ((l16 & 7) << 4);
    const int kx1 = kx0 ^ 64;
    const int arow = (wr * 64 + l16) * 128;     // byte row base in A region
    const int brow = ((wc & 1) * 64 + l16) * 128;
    // staging per-lane constants (inverse-swizzled global source)
    const int rsub = lane >> 3;                       // 0..7
    const int kf   = ((lane & 7) ^ rsub) << 3;        // f16 units
    const f16* Abase = A + (size_t)(bm * 256 + wid * 8 + rsub) * lda + kf;
    const f16* Bbase = W + (size_t)(bn * 256 + wid * 8 + rsub) * ldw + kf;

#define STAGE_A(DB, MH, KT) do { \
        const f16* g_ = Abase + (size_t)(MH) * 64 * lda + (size_t)(KT) * 64; \
        f16* d_ = (f16*)(lds + ((DB) * 2 + (MH)) * 16384 + wid * 1024); \
        gld16(g_, d_); gld16(g_ + (size_t)128 * lda, d_ + 4096); \
    } while (0)
#define STAGE_B(DB, NH, KT) do { \
        const f16* g_ = Bbase + (size_t)(NH) * 128 * ldw + (size_t)(KT) * 64; \
        f16* d_ = (f16*)(lds + 65536 + ((DB) * 2 + (NH)) * 16384 + wid * 1024); \
        gld16(g_, d_); gld16(g_ + (size_t)64 * ldw, d_ + 4096); \
    } while (0)
#define READ_A(DB, MH) do { \
        const char* r_ = lds + ((DB) * 2 + (MH)) * 16384 + arow; \
        _Pragma("unroll") for (int mf = 0; mf < 4; ++mf) { \
            af[mf][0] = *(const h8*)(r_ + mf * 2048 + kx0); \
            af[mf][1] = *(const h8*)(r_ + mf * 2048 + kx1); } \
    } while (0)
#define READ_B(DB, NG) do { \
        const char* r_ = lds + 65536 + ((DB) * 2 + nh) * 16384 + brow; \
        _Pragma("unroll") for (int nf = 0; nf < 2; ++nf) { \
            bf[(NG) * 2 + nf][0] = *(const h8*)(r_ + ((NG) * 2 + nf) * 2048 + kx0); \
            bf[(NG) * 2 + nf][1] = *(const h8*)(r_ + ((NG) * 2 + nf) * 2048 + kx1); } \
    } while (0)
#define MMA(MH, NG) do { \
        __builtin_amdgcn_s_setprio(1); \
        _Pragma("unroll") for (int nf = 0; nf < 2; ++nf) \
        _Pragma("unroll") for (int mf = 0; mf < 4; ++mf) \
        _Pragma("unroll") for (int kk = 0; kk < 2; ++kk) \
            acc[(MH) * 4 + mf][(NG) * 2 + nf] = __builtin_amdgcn_mfma_f32_16x16x32_f16( \
                af[mf][kk], bf[(NG) * 2 + nf][kk], acc[(MH) * 4 + mf][(NG) * 2 + nf], 0, 0, 0); \
        __builtin_amdgcn_s_setprio(0); \
    } while (0)

    fx4 acc[8][4] = {};
    h8 af[4][2], bf[4][2];

    // prologue: tile0 -> db0 (all 4 regions), tile1 -> db1.A0
    STAGE_A(0, 0, 0); STAGE_A(0, 1, 0); STAGE_B(0, 0, 0); STAGE_B(0, 1, 0);
    STAGE_A(1, 0, 1);
    VMC2;  // tile0 resident; db1.A0 (2 loads) may stay in flight
    BAR;

    const int NI = K >> 7;  // iterations of 2 K-tiles
    for (int i = 0; i < NI; ++i) {
        const int t1 = 2 * i + 1, n0 = 2 * i + 2, n1 = 2 * i + 3;
        const bool more = (i + 1 < NI);
        // ph1 (db0,mh0,ng0)
        READ_A(0, 0); READ_B(0, 0);
        STAGE_A(1, 1, t1);
        BAR; LGK0; MMA(0, 0); BAR;
        // ph2 (db0,mh0,ng1)
        READ_B(0, 1);
        STAGE_B(1, 0, t1); STAGE_B(1, 1, t1);
        BAR; LGK0; MMA(0, 1); BAR;
        // ph3 (db0,mh1,ng0)
        READ_A(0, 1);
        if (more) STAGE_A(0, 0, n0);
        BAR; LGK0; MMA(1, 0); BAR;
        // ph4 (db0,mh1,ng1)
        if (more) STAGE_B(0, 0, n0);
        BAR; MMA(1, 1);
        if (more) { VMC4; } else { VMC0; }   // drain all of db1<-t1
        BAR;
        // ph5 (db1,mh0,ng0)
        READ_A(1, 0); READ_B(1, 0);
        if (more) STAGE_A(0, 1, n0);
        BAR; LGK0; MMA(0, 0); BAR;
        // ph6 (db1,mh0,ng1)
        READ_B(1, 1);
        if (more) STAGE_B(0, 1, n0);
        BAR; LGK0; MMA(0, 1); BAR;
        // ph7 (db1,mh1,ng0)
        READ_A(1, 1);
        BAR; LGK0; MMA(1, 0); BAR;
        // ph8 (db1,mh1,ng1)
        if (more) STAGE_A(1, 0, n1);
        BAR; MMA(1, 1); VMC2; BAR;           // drain all of db0<-n0
    }

    // epilogue: C/D frag mapping col=lane&15, row=(lane>>4)*4+j
    const int rbase = bm * 256 + wr * 128;
    const int cbase = bn * 256 + wc * 64;
#pragma unroll
    for (int mf = 0; mf < 8; ++mf) {
#pragma unroll
        for (int nf = 0; nf < 4; ++nf) {
            const int col = cbase + nf * 16 + l16;
            float bv = 0.0f;
            if (EPI != 3) bv = bias[col];
#pragma unroll
            for (int j = 0; j < 4; ++j) {
                const int row = rbase + mf * 16 + kg * 4 + j;
                const size_t off = (size_t)row * N + col;
                float v = acc[mf][nf][j];
                if (EPI == 3) {
                    ((float*)Cv)[off] += v;
                } else {
                    v += bv;
                    if (EPI == 1) v = v / (1.0f + expf(-v));  // SiLU
                    if (EPI == 2) ((float*)Cv)[off] = v + res[off];
                    else          ((f16*)Cv)[off] = (f16)v;
                }
            }
        }
    }
#undef STAGE_A
#undef STAGE_B
#undef READ_A
#undef READ_B
#undef MMA
}

// --------------------------------------------------------- decayed scan
__device__ inline float head_decay(const float* decay_raw, int h) {
    const float dr = fminf(fmaxf(decay_raw[h], 0.9f), 1.0f);
    return powf(dr, 1.0f / (float)DC);
}

__global__ __launch_bounds__(256) void scan_carry(const f16* __restrict__ p,
                                                  const float* __restrict__ mix_w,
                                                  const float* __restrict__ decay_raw,
                                                  float* __restrict__ carry) {
    const int g = blockIdx.x * blockDim.x + threadIdx.x;  // NCH*NCHUNK
    const int e = g & (E - 1);
    const int chunk = (g >> 7) & (NCHUNK - 1);
    const int hb = g >> 13;                  // h*B + b
    const int h = hb >> 2, b = hb & 3;
    const float d = head_decay(decay_raw, h);
    const bool is_col = h < (H / 2);
    const int s0 = chunk * L;
    const f16* pp = p + ((size_t)(b * S + s0)) * D + h * E + e;
    const float* mw = mix_w + h * S + s0;
    float c = 0.0f;
#pragma unroll 4
    for (int i = 0; i < L; ++i) {
        float u = (float)pp[(size_t)i * D];
        if (!is_col) u *= mw[i];
        c = fmaf(d, c, u);
    }
    carry[chunk * NCH + hb * E + e] = c;
}

__global__ __launch_bounds__(256) void scan_prefix(const float* __restrict__ carry,
                                                   const float* __restrict__ decay_raw,
                                                   float* __restrict__ carry_in) {
    const int ch = blockIdx.x * blockDim.x + threadIdx.x;  // 0..NCH-1
    const int h = ch >> 9;                                  // /(B*E)=512
    const float d = head_decay(decay_raw, h);
    const float dL = powf(d, (float)L);
    float c = 0.0f;
    for (int j = 0; j < NCHUNK; ++j) {
        carry_in[j * NCH + ch] = c;
        c = fmaf(dL, c, carry[j * NCH + ch]);
    }
}

__global__ __launch_bounds__(256) void scan_apply(const f16* __restrict__ p,
                                                  const float* __restrict__ mix_w,
                                                  const float* __restrict__ mix_b,
                                                  const float* __restrict__ decay_raw,
                                                  const float* __restrict__ carry_in,
                                                  f16* __restrict__ mixed) {
    const int g = blockIdx.x * blockDim.x + threadIdx.x;
    const int e = g & (E - 1);
    const int chunk = (g >> 7) & (NCHUNK - 1);
    const int hb = g >> 13;
    const int h = hb >> 2, b = hb & 3;
    const float d = head_decay(decay_raw, h);
    const bool is_col = h < (H / 2);
    const int s0 = chunk * L;
    const f16* pp = p + ((size_t)(b * S + s0)) * D + h * E + e;
    f16* mo = mixed + ((size_t)(b * S + s0)) * D + h * E + e;
    const float* mw = mix_w + h * S + s0;
    const float* mb = mix_b + h * S + s0;
    float c = carry_in[chunk * NCH + hb * E + e];
#pragma unroll 4
    for (int i = 0; i < L; ++i) {
        const float w = mw[i];
        float u = (float)pp[(size_t)i * D];
        if (!is_col) u *= w;
        c = fmaf(d, c, u);
        float o = is_col ? fmaf(w, c, mb[i]) : (c + mb[i]);
        mo[(size_t)i * D] = (f16)o;
    }
}

// ------------------------------------------------------------------ launch
extern "C" void kernel_launch(void* const* d_in, const int* in_sizes, int n_in,
                              void* d_out, int out_size, void* d_ws, size_t ws_size,
                              hipStream_t stream) {
    (void)in_sizes; (void)n_in; (void)out_size; (void)ws_size;
    const float* x         = (const float*)d_in[0];
    const float* ln1_g     = (const float*)d_in[1];
    const float* ln1_b     = (const float*)d_in[2];
    const float* w1        = (const float*)d_in[3];
    const float* b1        = (const float*)d_in[4];
    const float* w2        = (const float*)d_in[5];
    const float* b2        = (const float*)d_in[6];
    const float* ln2_g     = (const float*)d_in[7];
    const float* ln2_b     = (const float*)d_in[8];
    const float* proj_w    = (const float*)d_in[9];   // [H,E,D] -> flat [D][D]
    const float* proj_b    = (const float*)d_in[10];  // [H,E]   -> flat [D]
    const float* mix_w     = (const float*)d_in[11];  // [H,S]
    const float* mix_b     = (const float*)d_in[12];  // [H,S]
    const float* decay_raw = (const float*)d_in[13];  // [H]
    const float* out_w     = (const float*)d_in[14];  // [D,D]
    const float* out_b     = (const float*)d_in[15];  // [D]
    float* out = (float*)d_out;

    // workspace (f16 unless noted), ~119 MB total:
    f16* lnbuf = (f16*)d_ws;
    f16* actc  = lnbuf + (size_t)M * D;
    f16* w1f   = actc + (size_t)M * FC;
    f16* w2f   = w1f + (size_t)F * D;
    f16* pjf   = w2f + (size_t)D * F;
    f16* owf   = pjf + (size_t)D * D;
    float* carry    = (float*)(owf + (size_t)D * D);
    float* carry_in = carry + (size_t)NCHUNK * NCH;
    f16* p     = actc;    // proj output reuses actc region
    f16* mixed = lnbuf;   // scan output reuses lnbuf region
    float* x2  = out;     // residual stream 2 lives in d_out

    const dim3 gD(D / 256, M / 256);   // (4, 64)
    const dim3 gC(FC / 256, M / 256);  // (8, 64)

    // 0) weights fp32 -> f16
    cvt_f16<<<1024, 256, 0, stream>>>(w1, w1f, F * D);
    cvt_f16<<<1024, 256, 0, stream>>>(w2, w2f, D * F);
    cvt_f16<<<256, 256, 0, stream>>>(proj_w, pjf, D * D);
    cvt_f16<<<256, 256, 0, stream>>>(out_w, owf, D * D);
    // 1) LN1
    ln_f16<<<M, 256, 0, stream>>>(x, ln1_g, ln1_b, lnbuf);
    // 2) MLP in 2 F-chunks
    hgemm256<1><<<gC, 512, 0, stream>>>(lnbuf, w1f, b1, nullptr, actc, D, D, D, FC);
    hgemm256<2><<<gD, 512, 0, stream>>>(actc, w2f, b2, x, x2, FC, FC, F, D);
    hgemm256<1><<<gC, 512, 0, stream>>>(lnbuf, w1f + (size_t)FC * D, b1 + FC, nullptr, actc, D, D, D, FC);
    hgemm256<3><<<gD, 512, 0, stream>>>(actc, w2f + FC, nullptr, nullptr, x2, FC, FC, F, D);
    // 3) LN2
    ln_f16<<<M, 256, 0, stream>>>(x2, ln2_g, ln2_b, lnbuf);
    // 4) p = lnbuf @ proj_w^T + proj_b
    hgemm256<0><<<gD, 512, 0, stream>>>(lnbuf, pjf, proj_b, nullptr, p, D, D, D, D);
    // 5) blocked linear scan
    scan_carry <<<(NCH * NCHUNK) / 256, 256, 0, stream>>>(p, mix_w, decay_raw, carry);
    scan_prefix<<<NCH / 256, 256, 0, stream>>>(carry, decay_raw, carry_in);
    scan_apply <<<(NCH * NCHUNK) / 256, 256, 0, stream>>>(p, mix_w, mix_b, decay_raw,
                                                          carry_in, mixed);
    // 6) out = mixed @ out_w^T + out_b + x2  (res aliases C; read-before-write)
    hgemm256<2><<<gD, 512, 0, stream>>>(mixed, owf, out_b, x2, out, D, D, D, D);
}

// Round 10
// 680.936 us; speedup vs baseline: 6.3325x; 1.0570x over previous
//
#include <hip/hip_runtime.h>
#include <math.h>

// Problem constants (match reference)
constexpr int B = 4, S = 4096, D = 1024, H = 8, EXPF = 4;
constexpr int E = D / H;        // 128
constexpr int F = EXPF * D;     // 4096
constexpr int M = B * S;        // 16384 rows
constexpr int DC = S / 512;     // 8
constexpr int FC = 2048;        // MLP F-chunk width (fallback path)
constexpr int L = 64;           // scan chunk length
constexpr int NCHUNK = S / L;   // 64
constexpr int NCH = H * B * E;  // 4096 scan channels

typedef _Float16 f16;
typedef f16  h8  __attribute__((ext_vector_type(8)));
typedef f16  h4  __attribute__((ext_vector_type(4)));
typedef float fx4 __attribute__((ext_vector_type(4)));

// async global->LDS, 16B per lane; lds dest is wave-uniform base + lane*16
__device__ __forceinline__ void gld16(const f16* g, f16* l) {
    __builtin_amdgcn_global_load_lds(
        (const __attribute__((address_space(1))) unsigned int*)g,
        (__attribute__((address_space(3))) unsigned int*)l, 16, 0, 0);
}

// ------------------------------------------------- fp32 -> f16 convert (x4)
__global__ __launch_bounds__(256) void cvt_all(const float* __restrict__ s0, f16* __restrict__ d0, int n0,
                                               const float* __restrict__ s1, f16* __restrict__ d1, int n1,
                                               const float* __restrict__ s2, f16* __restrict__ d2, int n2,
                                               const float* __restrict__ s3, f16* __restrict__ d3, int n3) {
    const int total = (n0 + n1 + n2 + n3) / 8;
    const int stride = gridDim.x * blockDim.x;
    for (int c = blockIdx.x * blockDim.x + threadIdx.x; c < total; c += stride) {
        int i = c * 8;
        const float* s; f16* d;
        if (i < n0)                { s = s0 + i;               d = d0 + i; }
        else if (i < n0 + n1)      { s = s1 + (i - n0);        d = d1 + (i - n0); }
        else if (i < n0 + n1 + n2) { s = s2 + (i - n0 - n1);   d = d2 + (i - n0 - n1); }
        else                       { s = s3 + (i - n0 - n1 - n2); d = d3 + (i - n0 - n1 - n2); }
        const float4 a = *(const float4*)s;
        const float4 b = *(const float4*)(s + 4);
        h8 o;
        o[0] = (f16)a.x; o[1] = (f16)a.y; o[2] = (f16)a.z; o[3] = (f16)a.w;
        o[4] = (f16)b.x; o[5] = (f16)b.y; o[6] = (f16)b.z; o[7] = (f16)b.w;
        *(h8*)d = o;
    }
}

// ---------------------------------------------------------------- LayerNorm
__global__ __launch_bounds__(256) void ln_f16(const float* __restrict__ x,
                                              const float* __restrict__ g,
                                              const float* __restrict__ b,
                                              f16* __restrict__ out) {
    const int row = blockIdx.x;
    const int t = threadIdx.x;                       // 256 threads, D/4 float4s
    const float4 v = ((const float4*)(x + (size_t)row * D))[t];
    float s  = v.x + v.y + v.z + v.w;
    float ss = v.x * v.x + v.y * v.y + v.z * v.z + v.w * v.w;
#pragma unroll
    for (int off = 32; off; off >>= 1) {
        s  += __shfl_xor(s, off, 64);
        ss += __shfl_xor(ss, off, 64);
    }
    __shared__ float sm[8];
    const int wave = t >> 6, lane = t & 63;
    if (lane == 0) { sm[wave] = s; sm[4 + wave] = ss; }
    __syncthreads();
    s  = sm[0] + sm[1] + sm[2] + sm[3];
    ss = sm[4] + sm[5] + sm[6] + sm[7];
    const float mean = s * (1.0f / D);
    const float var  = ss * (1.0f / D) - mean * mean;
    const float inv  = rsqrtf(var + 1e-5f);
    const float4 gg = ((const float4*)g)[t];
    const float4 bb = ((const float4*)b)[t];
    h4 o;
    o[0] = (f16)((v.x - mean) * inv * gg.x + bb.x);
    o[1] = (f16)((v.y - mean) * inv * gg.y + bb.y);
    o[2] = (f16)((v.z - mean) * inv * gg.z + bb.z);
    o[3] = (f16)((v.w - mean) * inv * gg.w + bb.w);
    *(h4*)(out + (size_t)row * D + t * 4) = o;
}

// ============================================================ 256x256 8-phase
// Structure identical to the round-8 PASSING kernel (same vmcnt ledger, same
// T2 swizzle). One change: T1 bijective XCD chunk-swizzle of (bm,bn) so blocks
// sharing an A row-panel land on the same XCD (A staged loads become L2 hits).
// Requires nwg % 8 == 0 (true for all launches here).
#define BAR  __builtin_amdgcn_s_barrier()
#define LGK0 asm volatile("s_waitcnt lgkmcnt(0)" ::: "memory")
#define VMC4 asm volatile("s_waitcnt vmcnt(4)" ::: "memory")
#define VMC2 asm volatile("s_waitcnt vmcnt(2)" ::: "memory")
#define VMC0 asm volatile("s_waitcnt vmcnt(0)" ::: "memory")

template <int EPI>
__global__ __launch_bounds__(512, 2) void hgemm256(const f16* __restrict__ A,
                                                   const f16* __restrict__ W,
                                                   const float* __restrict__ bias,
                                                   const float* res,  // may alias C
                                                   void* Cv,          // f16* or float*
                                                   int K, int lda, int ldw, int N) {
    __shared__ __align__(16) char lds[131072];  // 8 x 16KB regions
    const int t = threadIdx.x;
    const int wid = t >> 6, lane = t & 63;
    const int wr = wid >> 2, wc = wid & 3;      // 2 x 4 wave grid
    const int l16 = lane & 15, kg = lane >> 4;
    // T1: XCD chunk swizzle (dispatch id d -> XCD d%8 round-robin assumed;
    // give XCD x the contiguous logical chunk [x*cpx, (x+1)*cpx))
    const int nwg = gridDim.x * gridDim.y;
    const int d   = blockIdx.y * gridDim.x + blockIdx.x;
    const int cpx = nwg >> 3;
    const int Lw  = (d & 7) * cpx + (d >> 3);
    const int bn  = Lw % gridDim.x, bm = Lw / gridDim.x;
    const int nh = wc >> 1;                     // this wave's B region half

    // ds_read per-lane constants (swizzled)
    const int kx0 = (kg << 4) ^ ((l16 & 7) << 4);
    const int kx1 = kx0 ^ 64;
    const int arow = (wr * 64 + l16) * 128;     // byte row base in A region
    const int brow = ((wc & 1) * 64 + l16) * 128;
    // staging per-lane constants (inverse-swizzled global source)
    const int rsub = lane >> 3;                       // 0..7
    const int kf   = ((lane & 7) ^ rsub) << 3;        // f16 units
    const f16* Abase = A + (size_t)(bm * 256 + wid * 8 + rsub) * lda + kf;
    const f16* Bbase = W + (size_t)(bn * 256 + wid * 8 + rsub) * ldw + kf;

#define STAGE_A(DB, MH, KT) do { \
        const f16* g_ = Abase + (size_t)(MH) * 64 * lda + (size_t)(KT) * 64; \
        f16* d_ = (f16*)(lds + ((DB) * 2 + (MH)) * 16384 + wid * 1024); \
        gld16(g_, d_); gld16(g_ + (size_t)128 * lda, d_ + 4096); \
    } while (0)
#define STAGE_B(DB, NH, KT) do { \
        const f16* g_ = Bbase + (size_t)(NH) * 128 * ldw + (size_t)(KT) * 64; \
        f16* d_ = (f16*)(lds + 65536 + ((DB) * 2 + (NH)) * 16384 + wid * 1024); \
        gld16(g_, d_); gld16(g_ + (size_t)64 * ldw, d_ + 4096); \
    } while (0)
#define READ_A(DB, MH) do { \
        const char* r_ = lds + ((DB) * 2 + (MH)) * 16384 + arow; \
        _Pragma("unroll") for (int mf = 0; mf < 4; ++mf) { \
            af[mf][0] = *(const h8*)(r_ + mf * 2048 + kx0); \
            af[mf][1] = *(const h8*)(r_ + mf * 2048 + kx1); } \
    } while (0)
#define READ_B(DB, NG) do { \
        const char* r_ = lds + 65536 + ((DB) * 2 + nh) * 16384 + brow; \
        _Pragma("unroll") for (int nf = 0; nf < 2; ++nf) { \
            bf[(NG) * 2 + nf][0] = *(const h8*)(r_ + ((NG) * 2 + nf) * 2048 + kx0); \
            bf[(NG) * 2 + nf][1] = *(const h8*)(r_ + ((NG) * 2 + nf) * 2048 + kx1); } \
    } while (0)
#define MMA(MH, NG) do { \
        __builtin_amdgcn_s_setprio(1); \
        _Pragma("unroll") for (int nf = 0; nf < 2; ++nf) \
        _Pragma("unroll") for (int mf = 0; mf < 4; ++mf) \
        _Pragma("unroll") for (int kk = 0; kk < 2; ++kk) \
            acc[(MH) * 4 + mf][(NG) * 2 + nf] = __builtin_amdgcn_mfma_f32_16x16x32_f16( \
                af[mf][kk], bf[(NG) * 2 + nf][kk], acc[(MH) * 4 + mf][(NG) * 2 + nf], 0, 0, 0); \
        __builtin_amdgcn_s_setprio(0); \
    } while (0)

    fx4 acc[8][4] = {};
    h8 af[4][2], bf[4][2];

    // prologue: tile0 -> db0 (all 4 regions), tile1 -> db1.A0
    STAGE_A(0, 0, 0); STAGE_A(0, 1, 0); STAGE_B(0, 0, 0); STAGE_B(0, 1, 0);
    STAGE_A(1, 0, 1);
    VMC2;  // tile0 resident; db1.A0 (2 loads) may stay in flight
    BAR;

    const int NI = K >> 7;  // iterations of 2 K-tiles
    for (int i = 0; i < NI; ++i) {
        const int t1 = 2 * i + 1, n0 = 2 * i + 2, n1 = 2 * i + 3;
        const bool more = (i + 1 < NI);
        // ph1 (db0,mh0,ng0)
        READ_A(0, 0); READ_B(0, 0);
        STAGE_A(1, 1, t1);
        BAR; LGK0; MMA(0, 0); BAR;
        // ph2 (db0,mh0,ng1)
        READ_B(0, 1);
        STAGE_B(1, 0, t1); STAGE_B(1, 1, t1);
        BAR; LGK0; MMA(0, 1); BAR;
        // ph3 (db0,mh1,ng0)
        READ_A(0, 1);
        if (more) STAGE_A(0, 0, n0);
        BAR; LGK0; MMA(1, 0); BAR;
        // ph4 (db0,mh1,ng1)
        if (more) STAGE_B(0, 0, n0);
        BAR; MMA(1, 1);
        if (more) { VMC4; } else { VMC0; }   // drain all of db1<-t1
        BAR;
        // ph5 (db1,mh0,ng0)
        READ_A(1, 0); READ_B(1, 0);
        if (more) STAGE_A(0, 1, n0);
        BAR; LGK0; MMA(0, 0); BAR;
        // ph6 (db1,mh0,ng1)
        READ_B(1, 1);
        if (more) STAGE_B(0, 1, n0);
        BAR; LGK0; MMA(0, 1); BAR;
        // ph7 (db1,mh1,ng0)
        READ_A(1, 1);
        BAR; LGK0; MMA(1, 0); BAR;
        // ph8 (db1,mh1,ng1)
        if (more) STAGE_A(1, 0, n1);
        BAR; MMA(1, 1); VMC2; BAR;           // drain all of db0<-n0
    }

    // epilogue: C/D frag mapping col=lane&15, row=(lane>>4)*4+j
    const int rbase = bm * 256 + wr * 128;
    const int cbase = bn * 256 + wc * 64;
#pragma unroll
    for (int mf = 0; mf < 8; ++mf) {
#pragma unroll
        for (int nf = 0; nf < 4; ++nf) {
            const int col = cbase + nf * 16 + l16;
            float bv = 0.0f;
            if (EPI != 3) bv = bias[col];
#pragma unroll
            for (int j = 0; j < 4; ++j) {
                const int row = rbase + mf * 16 + kg * 4 + j;
                const size_t off = (size_t)row * N + col;
                float v = acc[mf][nf][j];
                if (EPI == 3) {
                    ((float*)Cv)[off] += v;
                } else {
                    v += bv;
                    if (EPI == 1) v = v / (1.0f + expf(-v));  // SiLU
                    if (EPI == 2) ((float*)Cv)[off] = v + res[off];
                    else          ((f16*)Cv)[off] = (f16)v;
                }
            }
        }
    }
#undef STAGE_A
#undef STAGE_B
#undef READ_A
#undef READ_B
#undef MMA
}

// --------------------------------------------------------- decayed scan
__device__ inline float head_decay(const float* decay_raw, int h) {
    const float dr = fminf(fmaxf(decay_raw[h], 0.9f), 1.0f);
    return powf(dr, 1.0f / (float)DC);
}

__global__ __launch_bounds__(256) void scan_carry(const f16* __restrict__ p,
                                                  const float* __restrict__ mix_w,
                                                  const float* __restrict__ decay_raw,
                                                  float* __restrict__ carry) {
    const int g = blockIdx.x * blockDim.x + threadIdx.x;  // NCH*NCHUNK
    const int e = g & (E - 1);
    const int chunk = (g >> 7) & (NCHUNK - 1);
    const int hb = g >> 13;                  // h*B + b
    const int h = hb >> 2, b = hb & 3;
    const float d = head_decay(decay_raw, h);
    const bool is_col = h < (H / 2);
    const int s0 = chunk * L;
    const f16* pp = p + ((size_t)(b * S + s0)) * D + h * E + e;
    const float* mw = mix_w + h * S + s0;
    float c = 0.0f;
#pragma unroll 4
    for (int i = 0; i < L; ++i) {
        float u = (float)pp[(size_t)i * D];
        if (!is_col) u *= mw[i];
        c = fmaf(d, c, u);
    }
    carry[chunk * NCH + hb * E + e] = c;
}

__global__ __launch_bounds__(256) void scan_prefix(const float* __restrict__ carry,
                                                   const float* __restrict__ decay_raw,
                                                   float* __restrict__ carry_in) {
    const int ch = blockIdx.x * blockDim.x + threadIdx.x;  // 0..NCH-1
    const int h = ch >> 9;                                  // /(B*E)=512
    const float d = head_decay(decay_raw, h);
    const float dL = powf(d, (float)L);
    float c = 0.0f;
    for (int j = 0; j < NCHUNK; ++j) {
        carry_in[j * NCH + ch] = c;
        c = fmaf(dL, c, carry[j * NCH + ch]);
    }
}

__global__ __launch_bounds__(256) void scan_apply(const f16* __restrict__ p,
                                                  const float* __restrict__ mix_w,
                                                  const float* __restrict__ mix_b,
                                                  const float* __restrict__ decay_raw,
                                                  const float* __restrict__ carry_in,
                                                  f16* __restrict__ mixed) {
    const int g = blockIdx.x * blockDim.x + threadIdx.x;
    const int e = g & (E - 1);
    const int chunk = (g >> 7) & (NCHUNK - 1);
    const int hb = g >> 13;
    const int h = hb >> 2, b = hb & 3;
    const float d = head_decay(decay_raw, h);
    const bool is_col = h < (H / 2);
    const int s0 = chunk * L;
    const f16* pp = p + ((size_t)(b * S + s0)) * D + h * E + e;
    f16* mo = mixed + ((size_t)(b * S + s0)) * D + h * E + e;
    const float* mw = mix_w + h * S + s0;
    const float* mb = mix_b + h * S + s0;
    float c = carry_in[chunk * NCH + hb * E + e];
#pragma unroll 4
    for (int i = 0; i < L; ++i) {
        const float w = mw[i];
        float u = (float)pp[(size_t)i * D];
        if (!is_col) u *= w;
        c = fmaf(d, c, u);
        float o = is_col ? fmaf(w, c, mb[i]) : (c + mb[i]);
        mo[(size_t)i * D] = (f16)o;
    }
}

// ------------------------------------------------------------------ launch
extern "C" void kernel_launch(void* const* d_in, const int* in_sizes, int n_in,
                              void* d_out, int out_size, void* d_ws, size_t ws_size,
                              hipStream_t stream) {
    (void)in_sizes; (void)n_in; (void)out_size;
    const float* x         = (const float*)d_in[0];
    const float* ln1_g     = (const float*)d_in[1];
    const float* ln1_b     = (const float*)d_in[2];
    const float* w1        = (const float*)d_in[3];
    const float* b1        = (const float*)d_in[4];
    const float* w2        = (const float*)d_in[5];
    const float* b2        = (const float*)d_in[6];
    const float* ln2_g     = (const float*)d_in[7];
    const float* ln2_b     = (const float*)d_in[8];
    const float* proj_w    = (const float*)d_in[9];   // [H,E,D] -> flat [D][D]
    const float* proj_b    = (const float*)d_in[10];  // [H,E]   -> flat [D]
    const float* mix_w     = (const float*)d_in[11];  // [H,S]
    const float* mix_b     = (const float*)d_in[12];  // [H,S]
    const float* decay_raw = (const float*)d_in[13];  // [H]
    const float* out_w     = (const float*)d_in[14];  // [D,D]
    const float* out_b     = (const float*)d_in[15];  // [D]
    float* out = (float*)d_out;
    float* x2  = out;     // residual stream 2 lives in d_out

    // Full-F path needs: lnbuf(M*D) + act(M*F) f16 + weights + carries ~191MB
    const size_t FULL_WS = (size_t)M * D * 2 + (size_t)M * F * 2 +
                           (size_t)F * D * 4 + (size_t)D * D * 4 +
                           (size_t)NCHUNK * NCH * 8;

    const dim3 gD(D / 256, M / 256);   // (4, 64)

    if (ws_size >= FULL_WS) {
        // ---------- full-F path: one GEMM1 (N=F), one GEMM2 (K=F) ----------
        f16* lnbuf = (f16*)d_ws;
        f16* act   = lnbuf + (size_t)M * D;
        f16* w1f   = act + (size_t)M * F;
        f16* w2f   = w1f + (size_t)F * D;
        f16* pjf   = w2f + (size_t)D * F;
        f16* owf   = pjf + (size_t)D * D;
        float* carry    = (float*)(owf + (size_t)D * D);
        float* carry_in = carry + (size_t)NCHUNK * NCH;
        f16* p     = act;     // proj output reuses act (free after GEMM2)
        f16* mixed = lnbuf;   // scan output reuses lnbuf (free after proj)

        cvt_all<<<2048, 256, 0, stream>>>(w1, w1f, F * D, w2, w2f, D * F,
                                          proj_w, pjf, D * D, out_w, owf, D * D);
        ln_f16<<<M, 256, 0, stream>>>(x, ln1_g, ln1_b, lnbuf);
        // act = silu(lnbuf @ w1^T + b1)        [M,F], grid (16,64)
        hgemm256<1><<<dim3(F / 256, M / 256), 512, 0, stream>>>(
            lnbuf, w1f, b1, nullptr, act, D, D, D, F);
        // x2 = act @ w2^T + b2 + x             [M,D], K=F
        hgemm256<2><<<gD, 512, 0, stream>>>(act, w2f, b2, x, x2, F, F, F, D);
        ln_f16<<<M, 256, 0, stream>>>(x2, ln2_g, ln2_b, lnbuf);
        hgemm256<0><<<gD, 512, 0, stream>>>(lnbuf, pjf, proj_b, nullptr, p, D, D, D, D);
        scan_carry <<<(NCH * NCHUNK) / 256, 256, 0, stream>>>(p, mix_w, decay_raw, carry);
        scan_prefix<<<NCH / 256, 256, 0, stream>>>(carry, decay_raw, carry_in);
        scan_apply <<<(NCH * NCHUNK) / 256, 256, 0, stream>>>(p, mix_w, mix_b, decay_raw,
                                                              carry_in, mixed);
        hgemm256<2><<<gD, 512, 0, stream>>>(mixed, owf, out_b, x2, out, D, D, D, D);
    } else {
        // ---------- fallback: proven chunked path (round-8) ----------
        f16* lnbuf = (f16*)d_ws;
        f16* actc  = lnbuf + (size_t)M * D;
        f16* w1f   = actc + (size_t)M * FC;
        f16* w2f   = w1f + (size_t)F * D;
        f16* pjf   = w2f + (size_t)D * F;
        f16* owf   = pjf + (size_t)D * D;
        float* carry    = (float*)(owf + (size_t)D * D);
        float* carry_in = carry + (size_t)NCHUNK * NCH;
        f16* p     = actc;
        f16* mixed = lnbuf;
        const dim3 gC(FC / 256, M / 256);

        cvt_all<<<2048, 256, 0, stream>>>(w1, w1f, F * D, w2, w2f, D * F,
                                          proj_w, pjf, D * D, out_w, owf, D * D);
        ln_f16<<<M, 256, 0, stream>>>(x, ln1_g, ln1_b, lnbuf);
        hgemm256<1><<<gC, 512, 0, stream>>>(lnbuf, w1f, b1, nullptr, actc, D, D, D, FC);
        hgemm256<2><<<gD, 512, 0, stream>>>(actc, w2f, b2, x, x2, FC, FC, F, D);
        hgemm256<1><<<gC, 512, 0, stream>>>(lnbuf, w1f + (size_t)FC * D, b1 + FC,
                                            nullptr, actc, D, D, D, FC);
        hgemm256<3><<<gD, 512, 0, stream>>>(actc, w2f + FC, nullptr, nullptr, x2, FC, FC, F, D);
        ln_f16<<<M, 256, 0, stream>>>(x2, ln2_g, ln2_b, lnbuf);
        hgemm256<0><<<gD, 512, 0, stream>>>(lnbuf, pjf, proj_b, nullptr, p, D, D, D, D);
        scan_carry <<<(NCH * NCHUNK) / 256, 256, 0, stream>>>(p, mix_w, decay_raw, carry);
        scan_prefix<<<NCH / 256, 256, 0, stream>>>(carry, decay_raw, carry_in);
        scan_apply <<<(NCH * NCHUNK) / 256, 256, 0, stream>>>(p, mix_w, mix_b, decay_raw,
                                                              carry_in, mixed);
        hgemm256<2><<<gD, 512, 0, stream>>>(mixed, owf, out_b, x2, out, D, D, D, D);
    }
}